// Round 18
// baseline (340.324 us; speedup 1.0000x reference)
//
#include <hip/hip_runtime.h>

// Problem constants
constexpr int N_NODES = 50000;
constexpr int E_EDGES = 800000;
constexpr int SLOTS   = 64;                     // fixed CSR capacity per node
constexpr int IN_DIM  = 128;
constexpr int HID     = 64;
constexpr int HEADS   = 4;
constexpr int HH      = HEADS * HID;            // 256
constexpr int EDGE_DIM = 8;
constexpr int L_LAYERS = 2;
constexpr float NEG_SLOPE = 0.2f;
constexpr int N_STRIPS = N_NODES / 16;          // 3125
constexpr int SCAT_BLKS = (E_EDGES + 1023) / 1024;  // 782 (4 edges/thread)
constexpr int PROJ_BLKS = (N_STRIPS + 15) / 16;   // 196
constexpr int CNT_BLKS  = 256;
constexpr int PAD_BLKS  = (N_NODES + 255) / 256;  // 196
constexpr int NBINS     = 32;                     // rounds <= 16

typedef float floatx2 __attribute__((ext_vector_type(2)));
typedef float f32x4 __attribute__((ext_vector_type(4)));
typedef short bf16x8 __attribute__((ext_vector_type(8)));

__device__ __forceinline__ unsigned short f2bf(float f) {
    unsigned int b = __float_as_uint(f);
    unsigned int r = (b + 0x7FFFu + ((b >> 16) & 1u)) >> 16;  // RNE
    return (unsigned short)r;
}
__device__ __forceinline__ float bf2f(unsigned short u) {
    return __uint_as_float(((unsigned int)u) << 16);
}

// fp8 e4m3 (OCP) pack/unpack via gfx950 HW converts
__device__ __forceinline__ unsigned char f2fp8(float v) {
    return (unsigned char)(__builtin_amdgcn_cvt_pk_fp8_f32(v, v, 0, false) & 0xFF);
}
__device__ __forceinline__ void fp8x4_to_f32(unsigned int w, float& a, float& b,
                                             float& c, float& d) {
    floatx2 lo = __builtin_amdgcn_cvt_pk_f32_fp8((int)w, false);
    floatx2 hi = __builtin_amdgcn_cvt_pk_f32_fp8((int)w, true);
    a = lo.x; b = lo.y; c = hi.x; d = hi.y;
}

// ---------------- MEGA: scatter(4/thread) | proj_mfma | count_attr ---
__global__ void mega_kernel(const int* __restrict__ src, const int* __restrict__ dst,
                            const int* __restrict__ attr, int* __restrict__ cnt,
                            unsigned int* __restrict__ fcsr, int* __restrict__ counts,
                            const float* __restrict__ x, const float* __restrict__ w,
                            const float* __restrict__ b, float* __restrict__ x0) {
    __shared__ unsigned short wS[IN_DIM * HID];  // proj weights bf16, 16 KB
    int bid = blockIdx.x;
    if (bid < SCAT_BLKS) {
        // ---- scatter: 4 edges/thread, independent atomic chains ----
        int base = bid * 1024 + threadIdx.x;
        int e0 = base, e1 = base + 256, e2 = base + 512, e3 = base + 768;
        bool v0 = e0 < E_EDGES, v1 = e1 < E_EDGES, v2 = e2 < E_EDGES, v3 = e3 < E_EDGES;
        int d0 = v0 ? dst[e0] : 0, d1 = v1 ? dst[e1] : 0;
        int d2 = v2 ? dst[e2] : 0, d3 = v3 ? dst[e3] : 0;
        unsigned int w0 = v0 ? ((unsigned int)src[e0] | ((unsigned int)attr[e0] << 16)) : 0;
        unsigned int w1 = v1 ? ((unsigned int)src[e1] | ((unsigned int)attr[e1] << 16)) : 0;
        unsigned int w2 = v2 ? ((unsigned int)src[e2] | ((unsigned int)attr[e2] << 16)) : 0;
        unsigned int w3 = v3 ? ((unsigned int)src[e3] | ((unsigned int)attr[e3] << 16)) : 0;
        int p0 = v0 ? atomicAdd(&cnt[d0], 1) : SLOTS;
        int p1 = v1 ? atomicAdd(&cnt[d1], 1) : SLOTS;
        int p2 = v2 ? atomicAdd(&cnt[d2], 1) : SLOTS;
        int p3 = v3 ? atomicAdd(&cnt[d3], 1) : SLOTS;
        if (p0 < SLOTS - 1) fcsr[((size_t)d0 << 6) + p0] = w0;
        if (p1 < SLOTS - 1) fcsr[((size_t)d1 << 6) + p1] = w1;
        if (p2 < SLOTS - 1) fcsr[((size_t)d2 << 6) + p2] = w2;
        if (p3 < SLOTS - 1) fcsr[((size_t)d3 << 6) + p3] = w3;
        return;
    }
    bid -= SCAT_BLKS;
    if (bid < PROJ_BLKS) {
        // ---- proj via MFMA: x0 = x @ proj_w + b ----
        for (int i = threadIdx.x; i < IN_DIM * HID; i += 256) wS[i] = f2bf(w[i]);
        __syncthreads();
        int wid = threadIdx.x >> 6, lane = threadIdx.x & 63;
        int colb = lane & 15, kb = (lane >> 4) * 8;
        bf16x8 bfr[4][4];
#pragma unroll
        for (int c = 0; c < 4; ++c)
#pragma unroll
            for (int g = 0; g < 4; ++g) {
                bf16x8 v;
#pragma unroll
                for (int j = 0; j < 8; ++j)
                    v[j] = (short)wS[(g * 32 + kb + j) * HID + c * 16 + colb];
                bfr[c][g] = v;
            }
        float bias_v[4];
#pragma unroll
        for (int c = 0; c < 4; ++c) bias_v[c] = b[c * 16 + colb];
#pragma unroll
        for (int i = 0; i < 4; ++i) {
            int s = bid * 16 + i * 4 + wid;
            if (s >= N_STRIPS) break;
            int row = s * 16 + colb;
            const float* xp = x + (size_t)row * IN_DIM + kb;
            bf16x8 af[4];
#pragma unroll
            for (int g = 0; g < 4; ++g) {
                float4 lo = *(const float4*)(xp + g * 32);
                float4 hi = *(const float4*)(xp + g * 32 + 4);
                bf16x8 v;
                v[0] = (short)f2bf(lo.x); v[1] = (short)f2bf(lo.y);
                v[2] = (short)f2bf(lo.z); v[3] = (short)f2bf(lo.w);
                v[4] = (short)f2bf(hi.x); v[5] = (short)f2bf(hi.y);
                v[6] = (short)f2bf(hi.z); v[7] = (short)f2bf(hi.w);
                af[g] = v;
            }
            int rbase = s * 16 + (lane >> 4) * 4;
#pragma unroll
            for (int c = 0; c < 4; ++c) {
                f32x4 acc = {0.f, 0.f, 0.f, 0.f};
#pragma unroll
                for (int g = 0; g < 4; ++g)
                    acc = __builtin_amdgcn_mfma_f32_16x16x32_bf16(af[g], bfr[c][g], acc, 0, 0, 0);
#pragma unroll
                for (int r = 0; r < 4; ++r)
                    x0[(size_t)(rbase + r) * HID + c * 16 + colb] = acc[r] + bias_v[c];
            }
        }
        return;
    }
    bid -= PROJ_BLKS;
    {
        // ---- count_attr: wave-reduced histogram ----
        int c0 = 0, c1 = 0, c2 = 0;
        for (int i = bid * 256 + threadIdx.x; i < E_EDGES; i += CNT_BLKS * 256) {
            int a = attr[i];
            c0 += (a == 0); c1 += (a == 1); c2 += (a == 2);
        }
        for (int o = 32; o; o >>= 1) {
            c0 += __shfl_down(c0, o);
            c1 += __shfl_down(c1, o);
            c2 += __shfl_down(c2, o);
        }
        if ((threadIdx.x & 63) == 0) {
            atomicAdd(&counts[0], c0);
            atomicAdd(&counts[1], c1);
            atomicAdd(&counts[2], c2);
        }
    }
}

// ---------------- PAD: self-loop + pad to 4 + round-hist (+eet) ------
__global__ void pad_eet_kernel(int* __restrict__ cnt, unsigned int* __restrict__ fcsr,
                               int* __restrict__ bins16,
                               const float* __restrict__ edge_emb, const float* __restrict__ We,
                               const int* __restrict__ counts, float* __restrict__ eet) {
    if (blockIdx.x >= (unsigned)PAD_BLKS) {
        // ---- eet[l][t][hc] for BOTH layers (single extra block) ----
        int hc = threadIdx.x;
        float inv = 1.f / (float)E_EDGES;
        for (int l = 0; l < L_LAYERS; ++l) {
            const float* We_l = We + (size_t)l * EDGE_DIM * HH;
            float* eet_l = eet + (size_t)l * 4 * HH;
            for (int t = 0; t < 3; ++t) {
                float acc = 0.f;
#pragma unroll
                for (int d = 0; d < EDGE_DIM; ++d) acc += edge_emb[t * EDGE_DIM + d] * We_l[d * HH + hc];
                eet_l[t * HH + hc] = acc;
            }
            float acc = 0.f;
#pragma unroll
            for (int d = 0; d < EDGE_DIM; ++d) {
                float md = (counts[0] * edge_emb[0 * EDGE_DIM + d] +
                            counts[1] * edge_emb[1 * EDGE_DIM + d] +
                            counts[2] * edge_emb[2 * EDGE_DIM + d]) * inv;
                acc += md * We_l[d * HH + hc];
            }
            eet_l[3 * HH + hc] = acc;
        }
        return;
    }
    __shared__ int h[NBINS];
    if (threadIdx.x < NBINS) h[threadIdx.x] = 0;
    __syncthreads();
    int n = blockIdx.x * 256 + threadIdx.x;
    if (n < N_NODES) {
        int c = cnt[n];
        if (c > SLOTS - 1) c = SLOTS - 1;  // defensive (scatter clamps stores)
        int tot = c + 1;                    // + self-loop
        int pad = (tot + 3) & ~3;
        unsigned int selfe = (unsigned int)n | (3u << 16);  // type 3 = mean edge feat
        unsigned int* row = fcsr + ((size_t)n << 6);
        for (int p = c; p < pad; ++p) row[p] = selfe;  // self at slot c, dummies after
        cnt[n] = tot;
        atomicAdd(&h[pad >> 2], 1);
    }
    __syncthreads();
    if (threadIdx.x < NBINS && h[threadIdx.x])
        atomicAdd(&bins16[threadIdx.x << 4], h[threadIdx.x]);
}

// ---------------- scan bins (descending) -> cursors ------------------
__global__ void scan_bins_kernel(const int* __restrict__ bins16, int* __restrict__ cur16) {
    int b = threadIdx.x;
    if (b < NBINS) {
        int base = 0;
        for (int j = NBINS - 1; j > b; --j) base += bins16[j << 4];
        cur16[b << 4] = base;  // descending order: big-round nodes first
    }
}

// ---------------- order: bucket nodes by rounds ----------------------
__global__ void order_kernel(const int* __restrict__ cnt, int* __restrict__ cur16,
                             int* __restrict__ order) {
    __shared__ int h[NBINS], base[NBINS], loc[NBINS];
    if (threadIdx.x < NBINS) { h[threadIdx.x] = 0; loc[threadIdx.x] = 0; }
    __syncthreads();
    int n = blockIdx.x * 256 + threadIdx.x;
    bool valid = n < N_NODES;
    int rb = 0;
    if (valid) {
        rb = (cnt[n] + 3) >> 2;
        atomicAdd(&h[rb], 1);
    }
    __syncthreads();
    if (threadIdx.x < NBINS && h[threadIdx.x])
        base[threadIdx.x] = atomicAdd(&cur16[threadIdx.x << 4], h[threadIdx.x]);
    __syncthreads();
    if (valid) {
        int r = atomicAdd(&loc[rb], 1);
        order[base[rb] + r] = n;
    }
}

// ---------------- transform via MFMA ---------------------------------
__global__ __launch_bounds__(256)
void transform_mfma_kernel(const float* __restrict__ x, const float* __restrict__ Wl,
                           const float* __restrict__ Wr, unsigned char* __restrict__ xl,
                           unsigned short* __restrict__ xr) {
    __shared__ unsigned short wS[HID * 512];  // [k][512] bf16 (Wl|Wr), 64 KB
    for (int i = threadIdx.x; i < HID * 512; i += 256) {
        int k = i >> 9, c = i & 511;
        float v = (c < 256) ? Wl[k * 256 + c] : Wr[k * 256 + (c - 256)];
        wS[i] = f2bf(v);
    }
    __syncthreads();
    int wid = threadIdx.x >> 6, lane = threadIdx.x & 63;
    int colb = lane & 15, kb = (lane >> 4) * 8;
    bf16x8 bfr[8][2];
#pragma unroll
    for (int c = 0; c < 8; ++c)
#pragma unroll
        for (int g = 0; g < 2; ++g) {
            bf16x8 v;
            int col = wid * 128 + c * 16 + colb;
#pragma unroll
            for (int j = 0; j < 8; ++j)
                v[j] = (short)wS[(g * 32 + kb + j) * 512 + col];
            bfr[c][g] = v;
        }

    for (int i = 0; i < 16; ++i) {
        int s = blockIdx.x * 16 + i;
        if (s >= N_STRIPS) break;
        int row = s * 16 + colb;
        const float* xp = x + (size_t)row * HID + kb;
        bf16x8 af[2];
#pragma unroll
        for (int g = 0; g < 2; ++g) {
            float4 lo = *(const float4*)(xp + g * 32);
            float4 hi = *(const float4*)(xp + g * 32 + 4);
            bf16x8 v;
            v[0] = (short)f2bf(lo.x); v[1] = (short)f2bf(lo.y);
            v[2] = (short)f2bf(lo.z); v[3] = (short)f2bf(lo.w);
            v[4] = (short)f2bf(hi.x); v[5] = (short)f2bf(hi.y);
            v[6] = (short)f2bf(hi.z); v[7] = (short)f2bf(hi.w);
            af[g] = v;
        }
        int rbase = s * 16 + (lane >> 4) * 4;
#pragma unroll
        for (int c = 0; c < 8; ++c) {
            f32x4 acc = {0.f, 0.f, 0.f, 0.f};
            acc = __builtin_amdgcn_mfma_f32_16x16x32_bf16(af[0], bfr[c][0], acc, 0, 0, 0);
            acc = __builtin_amdgcn_mfma_f32_16x16x32_bf16(af[1], bfr[c][1], acc, 0, 0, 0);
            int col = wid * 128 + c * 16 + colb;
            if (col < 256) {
#pragma unroll
                for (int r = 0; r < 4; ++r)
                    xl[(size_t)(rbase + r) * HH + col] = f2fp8(acc[r]);
            } else {
                int c2 = col - 256;
#pragma unroll
                for (int r = 0; r < 4; ++r)
                    xr[(size_t)(rbase + r) * HH + c2] = f2bf(acc[r]);
            }
        }
    }
}

// ---------------- Fused GAT: R16 structure + abs-trick + exp2 --------
// lrelu(m)*a = a*(0.6m + 0.4|m|); with a6=0.6*log2e*a, a4=0.4*log2e*a the
// per-channel cost is add,add,fma,fma (|m| is a free VOP3 abs modifier).
__global__ void gat_fused_kernel(const unsigned int* __restrict__ fcsr,
                                 const int* __restrict__ cnt,
                                 const int* __restrict__ order,
                                 const unsigned char* __restrict__ xl,
                                 const unsigned short* __restrict__ xr,
                                 const float* __restrict__ eet_l, const float* __restrict__ att_l,
                                 const float* __restrict__ bias_l, const float* __restrict__ lnw,
                                 const float* __restrict__ lnb, const float* __restrict__ x_res,
                                 float* __restrict__ x_out) {
    __shared__ float4 eetS[256];  // [4 types][64 lanes]
    eetS[threadIdx.x] = ((const float4*)eet_l)[threadIdx.x];
    __syncthreads();
    int n = order[blockIdx.x * 4 + (threadIdx.x >> 6)];
    int lane = threadIdx.x & 63;
    float4 av = *(const float4*)(att_l + lane * 4);
    float4 a6, a4;
    a6.x = av.x * (0.6f * 1.44269504f); a4.x = av.x * (0.4f * 1.44269504f);
    a6.y = av.y * (0.6f * 1.44269504f); a4.y = av.y * (0.4f * 1.44269504f);
    a6.z = av.z * (0.6f * 1.44269504f); a4.z = av.z * (0.4f * 1.44269504f);
    a6.w = av.w * (0.6f * 1.44269504f); a4.w = av.w * (0.4f * 1.44269504f);
    ushort4 xrv = *(const ushort4*)(xr + (size_t)n * HH + lane * 4);
    float xr0 = bf2f(xrv.x), xr1 = bf2f(xrv.y), xr2 = bf2f(xrv.z), xr3 = bf2f(xrv.w);
    const unsigned char* xlb = xl + lane * 4;  // per-lane channel base
    int cntn = cnt[n];                          // includes self-loop
    const unsigned int* cp = fcsr + ((size_t)n << 6);
    float accA0 = 0.f, accA1 = 0.f, accA2 = 0.f, accA3 = 0.f, denA = 0.f;
    float accB0 = 0.f, accB1 = 0.f, accB2 = 0.f, accB3 = 0.f, denB = 0.f;

    auto gat_round = [&](uint4 ew, unsigned int xw0, unsigned int xw1, unsigned int xw2,
                         unsigned int xw3, int rem) {
        int t0 = ew.x >> 16, t1 = ew.y >> 16, t2 = ew.z >> 16, t3 = ew.w >> 16;
        float4 ee0 = eetS[(t0 << 6) + lane];
        float4 ee1 = eetS[(t1 << 6) + lane];
        float4 ee2 = eetS[(t2 << 6) + lane];
        float4 ee3 = eetS[(t3 << 6) + lane];
        float a0, a1, a2, a3, b0, b1, b2, b3, c0, c1, c2, c3, d0, d1, d2, d3;
        fp8x4_to_f32(xw0, a0, a1, a2, a3);
        fp8x4_to_f32(xw1, b0, b1, b2, b3);
        fp8x4_to_f32(xw2, c0, c1, c2, c3);
        fp8x4_to_f32(xw3, d0, d1, d2, d3);
        float m;
        float p0, p1, p2, p3;
        m = a0 + xr0 + ee0.x; p0  = a6.x * m + a4.x * fabsf(m);
        m = a1 + xr1 + ee0.y; p0 += a6.y * m + a4.y * fabsf(m);
        m = a2 + xr2 + ee0.z; p0 += a6.z * m + a4.z * fabsf(m);
        m = a3 + xr3 + ee0.w; p0 += a6.w * m + a4.w * fabsf(m);
        m = b0 + xr0 + ee1.x; p1  = a6.x * m + a4.x * fabsf(m);
        m = b1 + xr1 + ee1.y; p1 += a6.y * m + a4.y * fabsf(m);
        m = b2 + xr2 + ee1.z; p1 += a6.z * m + a4.z * fabsf(m);
        m = b3 + xr3 + ee1.w; p1 += a6.w * m + a4.w * fabsf(m);
        m = c0 + xr0 + ee2.x; p2  = a6.x * m + a4.x * fabsf(m);
        m = c1 + xr1 + ee2.y; p2 += a6.y * m + a4.y * fabsf(m);
        m = c2 + xr2 + ee2.z; p2 += a6.z * m + a4.z * fabsf(m);
        m = c3 + xr3 + ee2.w; p2 += a6.w * m + a4.w * fabsf(m);
        m = d0 + xr0 + ee3.x; p3  = a6.x * m + a4.x * fabsf(m);
        m = d1 + xr1 + ee3.y; p3 += a6.y * m + a4.y * fabsf(m);
        m = d2 + xr2 + ee3.z; p3 += a6.z * m + a4.z * fabsf(m);
        m = d3 + xr3 + ee3.w; p3 += a6.w * m + a4.w * fabsf(m);
        p0 += __shfl_xor(p0, 1); p1 += __shfl_xor(p1, 1);
        p2 += __shfl_xor(p2, 1); p3 += __shfl_xor(p3, 1);
        p0 += __shfl_xor(p0, 2); p1 += __shfl_xor(p1, 2);
        p2 += __shfl_xor(p2, 2); p3 += __shfl_xor(p3, 2);
        p0 += __shfl_xor(p0, 4); p1 += __shfl_xor(p1, 4);
        p2 += __shfl_xor(p2, 4); p3 += __shfl_xor(p3, 4);
        p0 += __shfl_xor(p0, 8); p1 += __shfl_xor(p1, 8);
        p2 += __shfl_xor(p2, 8); p3 += __shfl_xor(p3, 8);
        float w0 = exp2f(p0);
        float w1 = (rem > 1) ? exp2f(p1) : 0.f;
        float w2 = (rem > 2) ? exp2f(p2) : 0.f;
        float w3 = (rem > 3) ? exp2f(p3) : 0.f;
        denA += w0 + w1;
        denB += w2 + w3;
        accA0 += w0 * a0 + w1 * b0;  accB0 += w2 * c0 + w3 * d0;
        accA1 += w0 * a1 + w1 * b1;  accB1 += w2 * c1 + w3 * d1;
        accA2 += w0 * a2 + w1 * b2;  accB2 += w2 * c2 + w3 * d2;
        accA3 += w0 * a3 + w1 * b3;  accB3 += w2 * c3 + w3 * d3;
    };

    int rounds = (cntn + 3) >> 2;
    uint4 ew = *(const uint4*)cp;
    unsigned int xw0 = *(const unsigned int*)(xlb + (size_t)(ew.x & 0xFFFFu) * HH);
    unsigned int xw1 = *(const unsigned int*)(xlb + (size_t)(ew.y & 0xFFFFu) * HH);
    unsigned int xw2 = *(const unsigned int*)(xlb + (size_t)(ew.z & 0xFFFFu) * HH);
    unsigned int xw3 = *(const unsigned int*)(xlb + (size_t)(ew.w & 0xFFFFu) * HH);
    for (int it = 1; it < rounds; ++it) {
        uint4 ewN = *(const uint4*)(cp + (it << 2));
        unsigned int yw0 = *(const unsigned int*)(xlb + (size_t)(ewN.x & 0xFFFFu) * HH);
        unsigned int yw1 = *(const unsigned int*)(xlb + (size_t)(ewN.y & 0xFFFFu) * HH);
        unsigned int yw2 = *(const unsigned int*)(xlb + (size_t)(ewN.z & 0xFFFFu) * HH);
        unsigned int yw3 = *(const unsigned int*)(xlb + (size_t)(ewN.w & 0xFFFFu) * HH);
        gat_round(ew, xw0, xw1, xw2, xw3, 4);  // all-but-last rounds are full
        ew = ewN; xw0 = yw0; xw1 = yw1; xw2 = yw2; xw3 = yw3;
    }
    gat_round(ew, xw0, xw1, xw2, xw3, cntn - ((rounds - 1) << 2));

    float inv = 1.f / (denA + denB);
    float r0 = (accA0 + accB0) * inv, r1 = (accA1 + accB1) * inv;
    float r2 = (accA2 + accB2) * inv, r3 = (accA3 + accB3) * inv;
    // sum across heads (lanes differing in bits 4,5)
    r0 += __shfl_xor(r0, 16); r1 += __shfl_xor(r1, 16);
    r2 += __shfl_xor(r2, 16); r3 += __shfl_xor(r3, 16);
    r0 += __shfl_xor(r0, 32); r1 += __shfl_xor(r1, 32);
    r2 += __shfl_xor(r2, 32); r3 += __shfl_xor(r3, 32);
    if (lane < 16) {
        float4 xc = *(const float4*)(x_res + (size_t)n * HID + lane * 4);
        float4 bb = *(const float4*)(bias_l + lane * 4);
        float h0 = 0.25f * r0 + bb.x + xc.x;
        float h1 = 0.25f * r1 + bb.y + xc.y;
        float h2 = 0.25f * r2 + bb.z + xc.z;
        float h3 = 0.25f * r3 + bb.w + xc.w;
        float sum = h0 + h1 + h2 + h3;
        sum += __shfl_xor(sum, 1); sum += __shfl_xor(sum, 2);
        sum += __shfl_xor(sum, 4); sum += __shfl_xor(sum, 8);
        float mu = sum * (1.f / 64.f);
        float d0_ = h0 - mu, d1_ = h1 - mu, d2_ = h2 - mu, d3_ = h3 - mu;
        float vs = d0_ * d0_ + d1_ * d1_ + d2_ * d2_ + d3_ * d3_;
        vs += __shfl_xor(vs, 1); vs += __shfl_xor(vs, 2);
        vs += __shfl_xor(vs, 4); vs += __shfl_xor(vs, 8);
        float rstd = rsqrtf(vs * (1.f / 64.f) + 1e-5f);
        float4 w4 = *(const float4*)(lnw + lane * 4);
        float4 b4 = *(const float4*)(lnb + lane * 4);
        float4 o;
        o.x = d0_ * rstd * w4.x + b4.x;
        o.y = d1_ * rstd * w4.y + b4.y;
        o.z = d2_ * rstd * w4.z + b4.z;
        o.w = d3_ * rstd * w4.w + b4.w;
        *(float4*)(x_out + (size_t)n * HID + lane * 4) = o;
    }
}

extern "C" void kernel_launch(void* const* d_in, const int* in_sizes, int n_in,
                              void* d_out, int out_size, void* d_ws, size_t ws_size,
                              hipStream_t stream) {
    const float* x_in     = (const float*)d_in[0];
    const int*   edge_idx = (const int*)d_in[1];
    const int*   attr     = (const int*)d_in[2];
    const float* proj_w   = (const float*)d_in[3];
    const float* proj_b   = (const float*)d_in[4];
    const float* edge_emb = (const float*)d_in[5];
    const float* Wl       = (const float*)d_in[6];
    const float* Wr       = (const float*)d_in[7];
    const float* We       = (const float*)d_in[8];
    const float* att      = (const float*)d_in[9];
    const float* bias     = (const float*)d_in[10];
    const float* ln_w     = (const float*)d_in[11];
    const float* ln_b     = (const float*)d_in[12];
    float* out = (float*)d_out;

    const int* src_idx = edge_idx;
    const int* dst_idx = edge_idx + E_EDGES;

    // Workspace layout
    float* ws = (float*)d_ws;
    float* x0 = ws;                                            // N*HID f32
    float* x1 = x0 + (size_t)N_NODES * HID;                    // N*HID f32
    unsigned char* xl_f8 = (unsigned char*)(x1 + (size_t)N_NODES * HID);     // N*HH u8
    unsigned short* xr_bf = (unsigned short*)(xl_f8 + (size_t)N_NODES * HH); // N*HH u16
    unsigned int* fcsr = (unsigned int*)(xr_bf + (size_t)N_NODES * HH);      // N*64 u32
    int* cnt    = (int*)(fcsr + (size_t)N_NODES * SLOTS);      // N (dense)
    int* counts = cnt + N_NODES;                               // 4
    int* bins16 = counts + 4;                                  // 32*16 (line-spread)
    int* cur16  = bins16 + NBINS * 16;                         // 32*16 (written by scan)
    int* order  = cur16 + NBINS * 16;                          // N
    float* eet  = (float*)(order + N_NODES);                   // L*4*HH

    // zero cnt + counts + bins16 in one memset
    hipMemsetAsync(cnt, 0, ((size_t)N_NODES + 4 + NBINS * 16) * sizeof(int), stream);

    mega_kernel<<<SCAT_BLKS + PROJ_BLKS + CNT_BLKS, 256, 0, stream>>>(
        src_idx, dst_idx, attr, cnt, fcsr, counts, x_in, proj_w, proj_b, x0);
    pad_eet_kernel<<<PAD_BLKS + 1, 256, 0, stream>>>(cnt, fcsr, bins16,
                                                     edge_emb, We, counts, eet);
    scan_bins_kernel<<<1, 64, 0, stream>>>(bins16, cur16);
    order_kernel<<<PAD_BLKS, 256, 0, stream>>>(cnt, cur16, order);
    transform_mfma_kernel<<<PROJ_BLKS, 256, 0, stream>>>(x0, Wl, Wr, xl_f8, xr_bf);
    gat_fused_kernel<<<N_NODES / 4, 256, 0, stream>>>(fcsr, cnt, order, xl_f8, xr_bf, eet,
                                                      att, bias, ln_w, ln_b, x0, x1);
    transform_mfma_kernel<<<PROJ_BLKS, 256, 0, stream>>>(x1, Wl + (size_t)HID * HH,
                                                         Wr + (size_t)HID * HH, xl_f8, xr_bf);
    gat_fused_kernel<<<N_NODES / 4, 256, 0, stream>>>(fcsr, cnt, order, xl_f8, xr_bf,
                                                      eet + 4 * HH, att + HH, bias + HID,
                                                      ln_w + HID, ln_b + HID, x1, out);
}

// Round 19
// 323.078 us; speedup vs baseline: 1.0534x; 1.0534x over previous
//
#include <hip/hip_runtime.h>

// Problem constants
constexpr int N_NODES = 50000;
constexpr int E_EDGES = 800000;
constexpr int SLOTS   = 64;                     // fixed CSR capacity per node
constexpr int IN_DIM  = 128;
constexpr int HID     = 64;
constexpr int HEADS   = 4;
constexpr int HH      = HEADS * HID;            // 256
constexpr int EDGE_DIM = 8;
constexpr int L_LAYERS = 2;
constexpr float NEG_SLOPE = 0.2f;
constexpr int N_STRIPS = N_NODES / 16;          // 3125
constexpr int SCAT_BLKS = (E_EDGES + 1023) / 1024;  // 782 (4 edges/thread)
constexpr int PROJ_BLKS = (N_STRIPS + 15) / 16;   // 196
constexpr int CNT_BLKS  = 256;
constexpr int PAD_BLKS  = (N_NODES + 255) / 256;  // 196
constexpr int NBINS     = 32;                     // rounds <= 16

typedef float floatx2 __attribute__((ext_vector_type(2)));
typedef float f32x4 __attribute__((ext_vector_type(4)));
typedef short bf16x8 __attribute__((ext_vector_type(8)));

__device__ __forceinline__ unsigned short f2bf(float f) {
    unsigned int b = __float_as_uint(f);
    unsigned int r = (b + 0x7FFFu + ((b >> 16) & 1u)) >> 16;  // RNE
    return (unsigned short)r;
}
__device__ __forceinline__ float bf2f(unsigned short u) {
    return __uint_as_float(((unsigned int)u) << 16);
}
__device__ __forceinline__ float lrelu(float x) { return fmaxf(x, NEG_SLOPE * x); }

// fp8 e4m3 (OCP) pack/unpack via gfx950 HW converts
__device__ __forceinline__ unsigned char f2fp8(float v) {
    return (unsigned char)(__builtin_amdgcn_cvt_pk_fp8_f32(v, v, 0, false) & 0xFF);
}
__device__ __forceinline__ void fp8x4_to_f32(unsigned int w, float& a, float& b,
                                             float& c, float& d) {
    floatx2 lo = __builtin_amdgcn_cvt_pk_f32_fp8((int)w, false);
    floatx2 hi = __builtin_amdgcn_cvt_pk_f32_fp8((int)w, true);
    a = lo.x; b = lo.y; c = hi.x; d = hi.y;
}

// ---------------- MEGA: scatter(4/thread) | proj_mfma | count_attr ---
__global__ void mega_kernel(const int* __restrict__ src, const int* __restrict__ dst,
                            const int* __restrict__ attr, int* __restrict__ cnt,
                            unsigned int* __restrict__ fcsr, int* __restrict__ counts,
                            const float* __restrict__ x, const float* __restrict__ w,
                            const float* __restrict__ b, float* __restrict__ x0) {
    __shared__ unsigned short wS[IN_DIM * HID];  // proj weights bf16, 16 KB
    int bid = blockIdx.x;
    if (bid < SCAT_BLKS) {
        // ---- scatter: 4 edges/thread, independent atomic chains ----
        int base = bid * 1024 + threadIdx.x;
        int e0 = base, e1 = base + 256, e2 = base + 512, e3 = base + 768;
        bool v0 = e0 < E_EDGES, v1 = e1 < E_EDGES, v2 = e2 < E_EDGES, v3 = e3 < E_EDGES;
        int d0 = v0 ? dst[e0] : 0, d1 = v1 ? dst[e1] : 0;
        int d2 = v2 ? dst[e2] : 0, d3 = v3 ? dst[e3] : 0;
        unsigned int w0 = v0 ? ((unsigned int)src[e0] | ((unsigned int)attr[e0] << 16)) : 0;
        unsigned int w1 = v1 ? ((unsigned int)src[e1] | ((unsigned int)attr[e1] << 16)) : 0;
        unsigned int w2 = v2 ? ((unsigned int)src[e2] | ((unsigned int)attr[e2] << 16)) : 0;
        unsigned int w3 = v3 ? ((unsigned int)src[e3] | ((unsigned int)attr[e3] << 16)) : 0;
        int p0 = v0 ? atomicAdd(&cnt[d0], 1) : SLOTS;
        int p1 = v1 ? atomicAdd(&cnt[d1], 1) : SLOTS;
        int p2 = v2 ? atomicAdd(&cnt[d2], 1) : SLOTS;
        int p3 = v3 ? atomicAdd(&cnt[d3], 1) : SLOTS;
        if (p0 < SLOTS - 1) fcsr[((size_t)d0 << 6) + p0] = w0;
        if (p1 < SLOTS - 1) fcsr[((size_t)d1 << 6) + p1] = w1;
        if (p2 < SLOTS - 1) fcsr[((size_t)d2 << 6) + p2] = w2;
        if (p3 < SLOTS - 1) fcsr[((size_t)d3 << 6) + p3] = w3;
        return;
    }
    bid -= SCAT_BLKS;
    if (bid < PROJ_BLKS) {
        // ---- proj via MFMA: x0 = x @ proj_w + b ----
        for (int i = threadIdx.x; i < IN_DIM * HID; i += 256) wS[i] = f2bf(w[i]);
        __syncthreads();
        int wid = threadIdx.x >> 6, lane = threadIdx.x & 63;
        int colb = lane & 15, kb = (lane >> 4) * 8;
        bf16x8 bfr[4][4];
#pragma unroll
        for (int c = 0; c < 4; ++c)
#pragma unroll
            for (int g = 0; g < 4; ++g) {
                bf16x8 v;
#pragma unroll
                for (int j = 0; j < 8; ++j)
                    v[j] = (short)wS[(g * 32 + kb + j) * HID + c * 16 + colb];
                bfr[c][g] = v;
            }
        float bias_v[4];
#pragma unroll
        for (int c = 0; c < 4; ++c) bias_v[c] = b[c * 16 + colb];
#pragma unroll
        for (int i = 0; i < 4; ++i) {
            int s = bid * 16 + i * 4 + wid;
            if (s >= N_STRIPS) break;
            int row = s * 16 + colb;
            const float* xp = x + (size_t)row * IN_DIM + kb;
            bf16x8 af[4];
#pragma unroll
            for (int g = 0; g < 4; ++g) {
                float4 lo = *(const float4*)(xp + g * 32);
                float4 hi = *(const float4*)(xp + g * 32 + 4);
                bf16x8 v;
                v[0] = (short)f2bf(lo.x); v[1] = (short)f2bf(lo.y);
                v[2] = (short)f2bf(lo.z); v[3] = (short)f2bf(lo.w);
                v[4] = (short)f2bf(hi.x); v[5] = (short)f2bf(hi.y);
                v[6] = (short)f2bf(hi.z); v[7] = (short)f2bf(hi.w);
                af[g] = v;
            }
            int rbase = s * 16 + (lane >> 4) * 4;
#pragma unroll
            for (int c = 0; c < 4; ++c) {
                f32x4 acc = {0.f, 0.f, 0.f, 0.f};
#pragma unroll
                for (int g = 0; g < 4; ++g)
                    acc = __builtin_amdgcn_mfma_f32_16x16x32_bf16(af[g], bfr[c][g], acc, 0, 0, 0);
#pragma unroll
                for (int r = 0; r < 4; ++r)
                    x0[(size_t)(rbase + r) * HID + c * 16 + colb] = acc[r] + bias_v[c];
            }
        }
        return;
    }
    bid -= PROJ_BLKS;
    {
        // ---- count_attr: wave-reduced histogram ----
        int c0 = 0, c1 = 0, c2 = 0;
        for (int i = bid * 256 + threadIdx.x; i < E_EDGES; i += CNT_BLKS * 256) {
            int a = attr[i];
            c0 += (a == 0); c1 += (a == 1); c2 += (a == 2);
        }
        for (int o = 32; o; o >>= 1) {
            c0 += __shfl_down(c0, o);
            c1 += __shfl_down(c1, o);
            c2 += __shfl_down(c2, o);
        }
        if ((threadIdx.x & 63) == 0) {
            atomicAdd(&counts[0], c0);
            atomicAdd(&counts[1], c1);
            atomicAdd(&counts[2], c2);
        }
    }
}

// ---------------- PAD: self-loop + pad to 4 + round-hist (+eet) ------
__global__ void pad_eet_kernel(int* __restrict__ cnt, unsigned int* __restrict__ fcsr,
                               int* __restrict__ bins16,
                               const float* __restrict__ edge_emb, const float* __restrict__ We,
                               const int* __restrict__ counts, float* __restrict__ eet) {
    if (blockIdx.x >= (unsigned)PAD_BLKS) {
        // ---- eet[l][t][hc] for BOTH layers (single extra block) ----
        int hc = threadIdx.x;
        float inv = 1.f / (float)E_EDGES;
        for (int l = 0; l < L_LAYERS; ++l) {
            const float* We_l = We + (size_t)l * EDGE_DIM * HH;
            float* eet_l = eet + (size_t)l * 4 * HH;
            for (int t = 0; t < 3; ++t) {
                float acc = 0.f;
#pragma unroll
                for (int d = 0; d < EDGE_DIM; ++d) acc += edge_emb[t * EDGE_DIM + d] * We_l[d * HH + hc];
                eet_l[t * HH + hc] = acc;
            }
            float acc = 0.f;
#pragma unroll
            for (int d = 0; d < EDGE_DIM; ++d) {
                float md = (counts[0] * edge_emb[0 * EDGE_DIM + d] +
                            counts[1] * edge_emb[1 * EDGE_DIM + d] +
                            counts[2] * edge_emb[2 * EDGE_DIM + d]) * inv;
                acc += md * We_l[d * HH + hc];
            }
            eet_l[3 * HH + hc] = acc;
        }
        return;
    }
    __shared__ int h[NBINS];
    if (threadIdx.x < NBINS) h[threadIdx.x] = 0;
    __syncthreads();
    int n = blockIdx.x * 256 + threadIdx.x;
    if (n < N_NODES) {
        int c = cnt[n];
        if (c > SLOTS - 1) c = SLOTS - 1;  // defensive (scatter clamps stores)
        int tot = c + 1;                    // + self-loop
        int pad = (tot + 3) & ~3;
        unsigned int selfe = (unsigned int)n | (3u << 16);  // type 3 = mean edge feat
        unsigned int* row = fcsr + ((size_t)n << 6);
        for (int p = c; p < pad; ++p) row[p] = selfe;  // self at slot c, dummies after
        cnt[n] = tot;
        atomicAdd(&h[pad >> 2], 1);
    }
    __syncthreads();
    if (threadIdx.x < NBINS && h[threadIdx.x])
        atomicAdd(&bins16[threadIdx.x << 4], h[threadIdx.x]);
}

// ---------------- scan bins (descending) -> cursors ------------------
__global__ void scan_bins_kernel(const int* __restrict__ bins16, int* __restrict__ cur16) {
    int b = threadIdx.x;
    if (b < NBINS) {
        int base = 0;
        for (int j = NBINS - 1; j > b; --j) base += bins16[j << 4];
        cur16[b << 4] = base;  // descending order: big-round nodes first
    }
}

// ---------------- order: bucket nodes by rounds ----------------------
__global__ void order_kernel(const int* __restrict__ cnt, int* __restrict__ cur16,
                             int* __restrict__ order) {
    __shared__ int h[NBINS], base[NBINS], loc[NBINS];
    if (threadIdx.x < NBINS) { h[threadIdx.x] = 0; loc[threadIdx.x] = 0; }
    __syncthreads();
    int n = blockIdx.x * 256 + threadIdx.x;
    bool valid = n < N_NODES;
    int rb = 0;
    if (valid) {
        rb = (cnt[n] + 3) >> 2;
        atomicAdd(&h[rb], 1);
    }
    __syncthreads();
    if (threadIdx.x < NBINS && h[threadIdx.x])
        base[threadIdx.x] = atomicAdd(&cur16[threadIdx.x << 4], h[threadIdx.x]);
    __syncthreads();
    if (valid) {
        int r = atomicAdd(&loc[rb], 1);
        order[base[rb] + r] = n;
    }
}

// ---------------- transform via MFMA ---------------------------------
__global__ __launch_bounds__(256)
void transform_mfma_kernel(const float* __restrict__ x, const float* __restrict__ Wl,
                           const float* __restrict__ Wr, unsigned char* __restrict__ xl,
                           unsigned short* __restrict__ xr) {
    __shared__ unsigned short wS[HID * 512];  // [k][512] bf16 (Wl|Wr), 64 KB
    for (int i = threadIdx.x; i < HID * 512; i += 256) {
        int k = i >> 9, c = i & 511;
        float v = (c < 256) ? Wl[k * 256 + c] : Wr[k * 256 + (c - 256)];
        wS[i] = f2bf(v);
    }
    __syncthreads();
    int wid = threadIdx.x >> 6, lane = threadIdx.x & 63;
    int colb = lane & 15, kb = (lane >> 4) * 8;
    bf16x8 bfr[8][2];
#pragma unroll
    for (int c = 0; c < 8; ++c)
#pragma unroll
        for (int g = 0; g < 2; ++g) {
            bf16x8 v;
            int col = wid * 128 + c * 16 + colb;
#pragma unroll
            for (int j = 0; j < 8; ++j)
                v[j] = (short)wS[(g * 32 + kb + j) * 512 + col];
            bfr[c][g] = v;
        }

    for (int i = 0; i < 16; ++i) {
        int s = blockIdx.x * 16 + i;
        if (s >= N_STRIPS) break;
        int row = s * 16 + colb;
        const float* xp = x + (size_t)row * HID + kb;
        bf16x8 af[2];
#pragma unroll
        for (int g = 0; g < 2; ++g) {
            float4 lo = *(const float4*)(xp + g * 32);
            float4 hi = *(const float4*)(xp + g * 32 + 4);
            bf16x8 v;
            v[0] = (short)f2bf(lo.x); v[1] = (short)f2bf(lo.y);
            v[2] = (short)f2bf(lo.z); v[3] = (short)f2bf(lo.w);
            v[4] = (short)f2bf(hi.x); v[5] = (short)f2bf(hi.y);
            v[6] = (short)f2bf(hi.z); v[7] = (short)f2bf(hi.w);
            af[g] = v;
        }
        int rbase = s * 16 + (lane >> 4) * 4;
#pragma unroll
        for (int c = 0; c < 8; ++c) {
            f32x4 acc = {0.f, 0.f, 0.f, 0.f};
            acc = __builtin_amdgcn_mfma_f32_16x16x32_bf16(af[0], bfr[c][0], acc, 0, 0, 0);
            acc = __builtin_amdgcn_mfma_f32_16x16x32_bf16(af[1], bfr[c][1], acc, 0, 0, 0);
            int col = wid * 128 + c * 16 + colb;
            if (col < 256) {
#pragma unroll
                for (int r = 0; r < 4; ++r)
                    xl[(size_t)(rbase + r) * HH + col] = f2fp8(acc[r]);
            } else {
                int c2 = col - 256;
#pragma unroll
                for (int r = 0; r < 4; ++r)
                    xr[(size_t)(rbase + r) * HH + c2] = f2bf(acc[r]);
            }
        }
    }
}

// ---------------- Fused GAT: R16-proven body (best measured) ---------
// 1 wave/node; prefetch-1 pipeline; scalar lrelu + __expf; 4KB eetS;
// degree-bucketed order.
__global__ void gat_fused_kernel(const unsigned int* __restrict__ fcsr,
                                 const int* __restrict__ cnt,
                                 const int* __restrict__ order,
                                 const unsigned char* __restrict__ xl,
                                 const unsigned short* __restrict__ xr,
                                 const float* __restrict__ eet_l, const float* __restrict__ att_l,
                                 const float* __restrict__ bias_l, const float* __restrict__ lnw,
                                 const float* __restrict__ lnb, const float* __restrict__ x_res,
                                 float* __restrict__ x_out) {
    __shared__ float4 eetS[256];  // [4 types][64 lanes]
    eetS[threadIdx.x] = ((const float4*)eet_l)[threadIdx.x];
    __syncthreads();
    int n = order[blockIdx.x * 4 + (threadIdx.x >> 6)];
    int lane = threadIdx.x & 63;
    float4 av = *(const float4*)(att_l + lane * 4);
    ushort4 xrv = *(const ushort4*)(xr + (size_t)n * HH + lane * 4);
    float xr0 = bf2f(xrv.x), xr1 = bf2f(xrv.y), xr2 = bf2f(xrv.z), xr3 = bf2f(xrv.w);
    const unsigned char* xlb = xl + lane * 4;  // per-lane channel base
    int cntn = cnt[n];                          // includes self-loop
    const unsigned int* cp = fcsr + ((size_t)n << 6);
    float accA0 = 0.f, accA1 = 0.f, accA2 = 0.f, accA3 = 0.f, denA = 0.f;
    float accB0 = 0.f, accB1 = 0.f, accB2 = 0.f, accB3 = 0.f, denB = 0.f;

    auto gat_round = [&](uint4 ew, unsigned int xw0, unsigned int xw1, unsigned int xw2,
                         unsigned int xw3, int rem) {
        int t0 = ew.x >> 16, t1 = ew.y >> 16, t2 = ew.z >> 16, t3 = ew.w >> 16;
        float4 ee0 = eetS[(t0 << 6) + lane];
        float4 ee1 = eetS[(t1 << 6) + lane];
        float4 ee2 = eetS[(t2 << 6) + lane];
        float4 ee3 = eetS[(t3 << 6) + lane];
        float a0, a1, a2, a3, b0, b1, b2, b3, c0, c1, c2, c3, d0, d1, d2, d3;
        fp8x4_to_f32(xw0, a0, a1, a2, a3);
        fp8x4_to_f32(xw1, b0, b1, b2, b3);
        fp8x4_to_f32(xw2, c0, c1, c2, c3);
        fp8x4_to_f32(xw3, d0, d1, d2, d3);
        float p0 = lrelu(a0 + xr0 + ee0.x) * av.x + lrelu(a1 + xr1 + ee0.y) * av.y +
                   lrelu(a2 + xr2 + ee0.z) * av.z + lrelu(a3 + xr3 + ee0.w) * av.w;
        float p1 = lrelu(b0 + xr0 + ee1.x) * av.x + lrelu(b1 + xr1 + ee1.y) * av.y +
                   lrelu(b2 + xr2 + ee1.z) * av.z + lrelu(b3 + xr3 + ee1.w) * av.w;
        float p2 = lrelu(c0 + xr0 + ee2.x) * av.x + lrelu(c1 + xr1 + ee2.y) * av.y +
                   lrelu(c2 + xr2 + ee2.z) * av.z + lrelu(c3 + xr3 + ee2.w) * av.w;
        float p3 = lrelu(d0 + xr0 + ee3.x) * av.x + lrelu(d1 + xr1 + ee3.y) * av.y +
                   lrelu(d2 + xr2 + ee3.z) * av.z + lrelu(d3 + xr3 + ee3.w) * av.w;
        p0 += __shfl_xor(p0, 1); p1 += __shfl_xor(p1, 1);
        p2 += __shfl_xor(p2, 1); p3 += __shfl_xor(p3, 1);
        p0 += __shfl_xor(p0, 2); p1 += __shfl_xor(p1, 2);
        p2 += __shfl_xor(p2, 2); p3 += __shfl_xor(p3, 2);
        p0 += __shfl_xor(p0, 4); p1 += __shfl_xor(p1, 4);
        p2 += __shfl_xor(p2, 4); p3 += __shfl_xor(p3, 4);
        p0 += __shfl_xor(p0, 8); p1 += __shfl_xor(p1, 8);
        p2 += __shfl_xor(p2, 8); p3 += __shfl_xor(p3, 8);
        float w0 = __expf(p0);
        float w1 = (rem > 1) ? __expf(p1) : 0.f;
        float w2 = (rem > 2) ? __expf(p2) : 0.f;
        float w3 = (rem > 3) ? __expf(p3) : 0.f;
        denA += w0 + w1;
        denB += w2 + w3;
        accA0 += w0 * a0 + w1 * b0;  accB0 += w2 * c0 + w3 * d0;
        accA1 += w0 * a1 + w1 * b1;  accB1 += w2 * c1 + w3 * d1;
        accA2 += w0 * a2 + w1 * b2;  accB2 += w2 * c2 + w3 * d2;
        accA3 += w0 * a3 + w1 * b3;  accB3 += w2 * c3 + w3 * d3;
    };

    int rounds = (cntn + 3) >> 2;
    uint4 ew = *(const uint4*)cp;
    unsigned int xw0 = *(const unsigned int*)(xlb + (size_t)(ew.x & 0xFFFFu) * HH);
    unsigned int xw1 = *(const unsigned int*)(xlb + (size_t)(ew.y & 0xFFFFu) * HH);
    unsigned int xw2 = *(const unsigned int*)(xlb + (size_t)(ew.z & 0xFFFFu) * HH);
    unsigned int xw3 = *(const unsigned int*)(xlb + (size_t)(ew.w & 0xFFFFu) * HH);
    for (int it = 1; it < rounds; ++it) {
        uint4 ewN = *(const uint4*)(cp + (it << 2));
        unsigned int yw0 = *(const unsigned int*)(xlb + (size_t)(ewN.x & 0xFFFFu) * HH);
        unsigned int yw1 = *(const unsigned int*)(xlb + (size_t)(ewN.y & 0xFFFFu) * HH);
        unsigned int yw2 = *(const unsigned int*)(xlb + (size_t)(ewN.z & 0xFFFFu) * HH);
        unsigned int yw3 = *(const unsigned int*)(xlb + (size_t)(ewN.w & 0xFFFFu) * HH);
        gat_round(ew, xw0, xw1, xw2, xw3, 4);  // all-but-last rounds are full
        ew = ewN; xw0 = yw0; xw1 = yw1; xw2 = yw2; xw3 = yw3;
    }
    gat_round(ew, xw0, xw1, xw2, xw3, cntn - ((rounds - 1) << 2));

    float inv = 1.f / (denA + denB);
    float r0 = (accA0 + accB0) * inv, r1 = (accA1 + accB1) * inv;
    float r2 = (accA2 + accB2) * inv, r3 = (accA3 + accB3) * inv;
    // sum across heads (lanes differing in bits 4,5)
    r0 += __shfl_xor(r0, 16); r1 += __shfl_xor(r1, 16);
    r2 += __shfl_xor(r2, 16); r3 += __shfl_xor(r3, 16);
    r0 += __shfl_xor(r0, 32); r1 += __shfl_xor(r1, 32);
    r2 += __shfl_xor(r2, 32); r3 += __shfl_xor(r3, 32);
    if (lane < 16) {
        float4 xc = *(const float4*)(x_res + (size_t)n * HID + lane * 4);
        float4 bb = *(const float4*)(bias_l + lane * 4);
        float h0 = 0.25f * r0 + bb.x + xc.x;
        float h1 = 0.25f * r1 + bb.y + xc.y;
        float h2 = 0.25f * r2 + bb.z + xc.z;
        float h3 = 0.25f * r3 + bb.w + xc.w;
        float sum = h0 + h1 + h2 + h3;
        sum += __shfl_xor(sum, 1); sum += __shfl_xor(sum, 2);
        sum += __shfl_xor(sum, 4); sum += __shfl_xor(sum, 8);
        float mu = sum * (1.f / 64.f);
        float d0_ = h0 - mu, d1_ = h1 - mu, d2_ = h2 - mu, d3_ = h3 - mu;
        float vs = d0_ * d0_ + d1_ * d1_ + d2_ * d2_ + d3_ * d3_;
        vs += __shfl_xor(vs, 1); vs += __shfl_xor(vs, 2);
        vs += __shfl_xor(vs, 4); vs += __shfl_xor(vs, 8);
        float rstd = rsqrtf(vs * (1.f / 64.f) + 1e-5f);
        float4 w4 = *(const float4*)(lnw + lane * 4);
        float4 b4 = *(const float4*)(lnb + lane * 4);
        float4 o;
        o.x = d0_ * rstd * w4.x + b4.x;
        o.y = d1_ * rstd * w4.y + b4.y;
        o.z = d2_ * rstd * w4.z + b4.z;
        o.w = d3_ * rstd * w4.w + b4.w;
        *(float4*)(x_out + (size_t)n * HID + lane * 4) = o;
    }
}

extern "C" void kernel_launch(void* const* d_in, const int* in_sizes, int n_in,
                              void* d_out, int out_size, void* d_ws, size_t ws_size,
                              hipStream_t stream) {
    const float* x_in     = (const float*)d_in[0];
    const int*   edge_idx = (const int*)d_in[1];
    const int*   attr     = (const int*)d_in[2];
    const float* proj_w   = (const float*)d_in[3];
    const float* proj_b   = (const float*)d_in[4];
    const float* edge_emb = (const float*)d_in[5];
    const float* Wl       = (const float*)d_in[6];
    const float* Wr       = (const float*)d_in[7];
    const float* We       = (const float*)d_in[8];
    const float* att      = (const float*)d_in[9];
    const float* bias     = (const float*)d_in[10];
    const float* ln_w     = (const float*)d_in[11];
    const float* ln_b     = (const float*)d_in[12];
    float* out = (float*)d_out;

    const int* src_idx = edge_idx;
    const int* dst_idx = edge_idx + E_EDGES;

    // Workspace layout
    float* ws = (float*)d_ws;
    float* x0 = ws;                                            // N*HID f32
    float* x1 = x0 + (size_t)N_NODES * HID;                    // N*HID f32
    unsigned char* xl_f8 = (unsigned char*)(x1 + (size_t)N_NODES * HID);     // N*HH u8
    unsigned short* xr_bf = (unsigned short*)(xl_f8 + (size_t)N_NODES * HH); // N*HH u16
    unsigned int* fcsr = (unsigned int*)(xr_bf + (size_t)N_NODES * HH);      // N*64 u32
    int* cnt    = (int*)(fcsr + (size_t)N_NODES * SLOTS);      // N (dense)
    int* counts = cnt + N_NODES;                               // 4
    int* bins16 = counts + 4;                                  // 32*16 (line-spread)
    int* cur16  = bins16 + NBINS * 16;                         // 32*16 (written by scan)
    int* order  = cur16 + NBINS * 16;                          // N
    float* eet  = (float*)(order + N_NODES);                   // L*4*HH

    // zero cnt + counts + bins16 in one memset
    hipMemsetAsync(cnt, 0, ((size_t)N_NODES + 4 + NBINS * 16) * sizeof(int), stream);

    mega_kernel<<<SCAT_BLKS + PROJ_BLKS + CNT_BLKS, 256, 0, stream>>>(
        src_idx, dst_idx, attr, cnt, fcsr, counts, x_in, proj_w, proj_b, x0);
    pad_eet_kernel<<<PAD_BLKS + 1, 256, 0, stream>>>(cnt, fcsr, bins16,
                                                     edge_emb, We, counts, eet);
    scan_bins_kernel<<<1, 64, 0, stream>>>(bins16, cur16);
    order_kernel<<<PAD_BLKS, 256, 0, stream>>>(cnt, cur16, order);
    transform_mfma_kernel<<<PROJ_BLKS, 256, 0, stream>>>(x0, Wl, Wr, xl_f8, xr_bf);
    gat_fused_kernel<<<N_NODES / 4, 256, 0, stream>>>(fcsr, cnt, order, xl_f8, xr_bf, eet,
                                                      att, bias, ln_w, ln_b, x0, x1);
    transform_mfma_kernel<<<PROJ_BLKS, 256, 0, stream>>>(x1, Wl + (size_t)HID * HH,
                                                         Wr + (size_t)HID * HH, xl_f8, xr_bf);
    gat_fused_kernel<<<N_NODES / 4, 256, 0, stream>>>(fcsr, cnt, order, xl_f8, xr_bf,
                                                      eet + 4 * HH, att + HH, bias + HID,
                                                      ln_w + HID, ln_b + HID, x1, out);
}